// Round 17
// baseline (1041.760 us; speedup 1.0000x reference)
//
#include <hip/hip_runtime.h>
#include <hip/hip_bf16.h>
#include <math.h>

typedef __hip_bfloat16 bf16;

#define B_ 4
#define S_ 4096
#define D_ 512
#define H_ 8
#define NC_ 64
#define M_ (B_*S_)     // 16384
#define BH_ (B_*H_)    // 32
#define QKVSTRIDE 8388608   // elems between qb/kb/vb (f32) and ck/cv (bf16)

typedef __attribute__((ext_vector_type(8))) short bfrag;
typedef __attribute__((ext_vector_type(4))) float facc;

static __device__ __forceinline__ float tof(float x){ return x; }
static __device__ __forceinline__ float tof(bf16 x){ return __bfloat162float(x); }

static __device__ __forceinline__ float4 ld4g(const float* p) {
    return *reinterpret_cast<const float4*>(p);
}
static __device__ __forceinline__ float4 ld4g(const bf16* p) {
    short4 s = *reinterpret_cast<const short4*>(p);
    float4 r;
    r.x = __bfloat162float(*reinterpret_cast<const bf16*>(&s.x));
    r.y = __bfloat162float(*reinterpret_cast<const bf16*>(&s.y));
    r.z = __bfloat162float(*reinterpret_cast<const bf16*>(&s.z));
    r.w = __bfloat162float(*reinterpret_cast<const bf16*>(&s.w));
    return r;
}
static __device__ __forceinline__ void st4(float* p, float4 v) {
    *reinterpret_cast<float4*>(p) = v;
}
static __device__ __forceinline__ void st4(bf16* p, float4 v) {
    bf16 b0 = __float2bfloat16(v.x), b1 = __float2bfloat16(v.y);
    bf16 b2 = __float2bfloat16(v.z), b3 = __float2bfloat16(v.w);
    short4 s;
    s.x = *reinterpret_cast<short*>(&b0);
    s.y = *reinterpret_cast<short*>(&b1);
    s.z = *reinterpret_cast<short*>(&b2);
    s.w = *reinterpret_cast<short*>(&b3);
    *reinterpret_cast<short4*>(p) = s;
}

#define GLL(gp, lp) __builtin_amdgcn_global_load_lds( \
    (const __attribute__((address_space(1))) void*)(gp), \
    (__attribute__((address_space(3))) void*)(lp), 16, 0, 0)

// ---------------------------------------------------------------------------
// Shared f32 GEMM block body (R8 config, best measured). Bit-identical
// accumulation order across all callers. PRECISION LEDGER: everything
// upstream of act0 (SA q/k/v, attn, Wo, proj) must be f32 — bf16-class
// noise anywhere in this chain flips CA hash buckets (R15/R16 failures).
// ---------------------------------------------------------------------------
#define F32_GEMM_BODY(A_, B_ptr, NB_, K_, row0_, col0_)                         \
    for (int k0 = 0; k0 < (K_); k0 += 32) {                                     \
        _Pragma("unroll")                                                       \
        for (int c = 0; c < 4; c++) {                                           \
            int e = c * 256 + tid;                                              \
            GLL((B_ptr) + (size_t)(k0 + (e >> 5)) * (NB_) + (col0_) + ((e & 31) << 2), \
                &Bs[c * 1024 + (wave << 8)]);                                   \
        }                                                                       \
        _Pragma("unroll")                                                       \
        for (int c = 0; c < 4; c++) {                                           \
            int e = c * 256 + tid;                                              \
            int r = e >> 3, k4 = (e & 7) << 2;                                  \
            float4 t4 = ld4g((A_) + (size_t)((row0_) + r) * (K_) + k0 + k4);    \
            At[k4 + 0][r] = t4.x;                                               \
            At[k4 + 1][r] = t4.y;                                               \
            At[k4 + 2][r] = t4.z;                                               \
            At[k4 + 3][r] = t4.w;                                               \
        }                                                                       \
        __syncthreads();                                                        \
        _Pragma("unroll")                                                       \
        for (int kk = 0; kk < 32; kk++) {                                       \
            float4 a0 = *reinterpret_cast<const float4*>(&At[kk][ty * 8]);      \
            float4 a1 = *reinterpret_cast<const float4*>(&At[kk][ty * 8 + 4]);  \
            float4 b0 = *reinterpret_cast<const float4*>(&Bs[kk * 128 + tx * 4]);\
            float4 b1 = *reinterpret_cast<const float4*>(&Bs[kk * 128 + 64 + tx * 4]);\
            float a[8] = {a0.x, a0.y, a0.z, a0.w, a1.x, a1.y, a1.z, a1.w};      \
            float bb[8] = {b0.x, b0.y, b0.z, b0.w, b1.x, b1.y, b1.z, b1.w};     \
            _Pragma("unroll")                                                   \
            for (int i = 0; i < 8; i++)                                         \
                _Pragma("unroll")                                               \
                for (int j = 0; j < 8; j++) acc[i][j] += a[i] * bb[j];          \
        }                                                                       \
        __syncthreads();                                                        \
    }

// ---------------------------------------------------------------------------
// f32 GEMM generic (sa_Wo path): C = A@B + res, f32 RM. N=512.
// ---------------------------------------------------------------------------
__global__ __launch_bounds__(256) void gemm_k(
    const float* __restrict__ A, const float* __restrict__ Bw,
    const float* __restrict__ res, float* __restrict__ out, int N, int K)
{
    __shared__ float At[32][132];
    __shared__ float Bs[32 * 128];
    int tid = threadIdx.x;
    int wave = tid >> 6;
    int nbx = N >> 7;
    int bx = blockIdx.x % nbx;
    int by = blockIdx.x / nbx;
    int row0 = by << 7, col0 = bx << 7;
    int ty = tid >> 4, tx = tid & 15;

    float acc[8][8];
    #pragma unroll
    for (int i = 0; i < 8; i++)
        #pragma unroll
        for (int j = 0; j < 8; j++) acc[i][j] = 0.f;

    F32_GEMM_BODY(A, Bw, N, K, row0, col0)

    #pragma unroll
    for (int i = 0; i < 8; i++) {
        int r = row0 + ty * 8 + i;
        #pragma unroll
        for (int j = 0; j < 8; j++) {
            int c = col0 + ((j >> 2) << 6) + tx * 4 + (j & 3);
            float v = acc[i][j];
            v += res[(size_t)r * N + c];
            out[(size_t)r * N + c] = v;
        }
    }
}

// ---------------------------------------------------------------------------
// Fused SA q/k/v GEMM (f32, hash-critical), XCD-chunked. 1536 blocks.
// Output scatter [B,H,S,64] into qb/kb/vb (QKVSTRIDE apart).
// ---------------------------------------------------------------------------
__global__ __launch_bounds__(256) void gemmqkv_k(
    const float* __restrict__ A, const float* __restrict__ W0,
    const float* __restrict__ W1, const float* __restrict__ W2,
    float* __restrict__ out)
{
    __shared__ float At[32][132];
    __shared__ float Bs[32 * 128];
    int tid = threadIdx.x;
    int wave = tid >> 6;
    int orig = blockIdx.x;
    int bid = (orig & 7) * 192 + (orig >> 3);   // bijective: 1536 = 8*192
    int bx = bid % 12;
    int by = bid / 12;
    int row0 = by << 7;
    int w = bx >> 2;
    int col0 = (bx & 3) << 7;
    const float* Bw = (w == 0) ? W0 : (w == 1) ? W1 : W2;
    float* outw = out + (size_t)w * QKVSTRIDE;
    int ty = tid >> 4, tx = tid & 15;

    float acc[8][8];
    #pragma unroll
    for (int i = 0; i < 8; i++)
        #pragma unroll
        for (int j = 0; j < 8; j++) acc[i][j] = 0.f;

    F32_GEMM_BODY(A, Bw, 512, 512, row0, col0)

    #pragma unroll
    for (int i = 0; i < 8; i++) {
        int r = row0 + ty * 8 + i;
        int b = r >> 12, s = r & (S_ - 1);
        #pragma unroll
        for (int j = 0; j < 8; j++) {
            int c = col0 + ((j >> 2) << 6) + tx * 4 + (j & 3);
            int h = c >> 6, kk2 = c & 63;
            outw[((size_t)(b * H_ + h) * S_ + s) * 64 + kk2] = acc[i][j];
        }
    }
}

// ---------------------------------------------------------------------------
// Batched hash projections WITH FUSED ARGMAX (round 17). z=0: act0@wrotq ->
// bq ; z=1: enc@wrotk -> bk. r values bit-identical to the standalone GEMM
// (same body, same k-order); argmax done in-register: each head's 32 cols
// live in 8 adjacent lanes (4 cols each). Lane-local scan (positives
// ascending then negations) + shfl_xor{1,2,4} reduce with
// (v>best)||(v==best && i<bi) = global first-index argmax, identical
// semantics to the serial scan. No rq/rk round-trip, no amax dispatch.
// ---------------------------------------------------------------------------
__global__ __launch_bounds__(256) void gemmproj_k(
    const float* __restrict__ A0, const float* __restrict__ B0, int* __restrict__ bq,
    const float* __restrict__ A1, const float* __restrict__ B1, int* __restrict__ bk)
{
    __shared__ float At[32][132];
    __shared__ float Bs[32 * 128];
    int tid = threadIdx.x;
    int wave = tid >> 6;
    int z = blockIdx.x >> 8;
    int bid = blockIdx.x & 255;
    int bx = bid & 1;
    int by = bid >> 1;
    int row0 = by << 7, col0 = bx << 7;
    const float* A = z ? A1 : A0;
    const float* Bw = z ? B1 : B0;
    int* bucket = z ? bk : bq;
    int ty = tid >> 4, tx = tid & 15;

    float acc[8][8];
    #pragma unroll
    for (int i = 0; i < 8; i++)
        #pragma unroll
        for (int j = 0; j < 8; j++) acc[i][j] = 0.f;

    F32_GEMM_BODY(A, Bw, 256, 512, row0, col0)

    // fused argmax epilogue: head_local = (j>>2)*2 + (tx>>3); idx-in-head
    // jj = (tx&7)*4 + (j&3). Reduce over the 8 lanes sharing (ty, tx>>3).
    #pragma unroll
    for (int i = 0; i < 8; i++) {
        int r = row0 + ty * 8 + i;
        int b = r >> 12, s = r & (S_ - 1);
        #pragma unroll
        for (int half = 0; half < 2; half++) {
            // lane-local first-index max over 8 candidates
            float bv = -INFINITY; int bi = 0;
            #pragma unroll
            for (int jj4 = 0; jj4 < 4; jj4++) {
                float v = acc[i][half * 4 + jj4];
                int idx = (tx & 7) * 4 + jj4;
                if (v > bv) { bv = v; bi = idx; }
            }
            #pragma unroll
            for (int jj4 = 0; jj4 < 4; jj4++) {
                float v = -acc[i][half * 4 + jj4];
                int idx = 32 + (tx & 7) * 4 + jj4;
                if (v > bv) { bv = v; bi = idx; }
            }
            // cross-lane reduce (8 adjacent lanes, same wave)
            #pragma unroll
            for (int off = 1; off < 8; off <<= 1) {
                float ov = __shfl_xor(bv, off, 64);
                int oi = __shfl_xor(bi, off, 64);
                if (ov > bv || (ov == bv && oi < bi)) { bv = ov; bi = oi; }
            }
            if ((tx & 7) == 0) {
                int h = bx * 4 + half * 2 + (tx >> 3);
                bucket[((size_t)(b * H_ + h)) * S_ + s] = bi;
            }
        }
    }
}

// ---------------------------------------------------------------------------
// bf16 MFMA GEMM. OUTMODE: 0 f32 RM, 1 bf16 RM.
// ---------------------------------------------------------------------------
#define MGEMM_CORE(A_, Bt_, K_, row0_, col0_)                                   \
    const short* gA = (A_) + (size_t)((row0_) + (wave << 5) + (lane >> 2)) * (K_) + ((lane & 3) << 3); \
    const short* gB = (Bt_) + (size_t)((col0_) + (wave << 5) + (lane >> 2)) * (K_) + ((lane & 3) << 3); \
    for (int k0 = 0; k0 < (K_); k0 += 32) {                                     \
        GLL(gA + k0,                    &As[wave << 10]);                       \
        GLL(gA + k0 + (size_t)16 * (K_), &As[(wave << 10) + 512]);              \
        GLL(gB + k0,                    &Bs[wave << 10]);                       \
        GLL(gB + k0 + (size_t)16 * (K_), &Bs[(wave << 10) + 512]);              \
        __syncthreads();                                                        \
        bfrag av[4], bv[4];                                                     \
        _Pragma("unroll")                                                       \
        for (int m = 0; m < 4; m++)                                             \
            av[m] = *reinterpret_cast<const bfrag*>(&As[(((wr << 6) + (m << 4) + fr) << 5) + (fq << 3)]); \
        _Pragma("unroll")                                                       \
        for (int n = 0; n < 4; n++)                                             \
            bv[n] = *reinterpret_cast<const bfrag*>(&Bs[(((wc << 6) + (n << 4) + fr) << 5) + (fq << 3)]); \
        _Pragma("unroll")                                                       \
        for (int m = 0; m < 4; m++)                                             \
            _Pragma("unroll")                                                   \
            for (int n = 0; n < 4; n++)                                         \
                acc[m][n] = __builtin_amdgcn_mfma_f32_16x16x32_bf16(av[m], bv[n], acc[m][n], 0, 0, 0); \
        __syncthreads();                                                        \
    }

template<int OUTMODE, int RES, bool BIAS, bool RELU>
__global__ __launch_bounds__(256) void mgemm_k(
    const short* __restrict__ A, const short* __restrict__ Bt,
    const float* __restrict__ bias, const float* __restrict__ res,
    void* __restrict__ out, int N, int K)
{
    __shared__ short As[128 * 32];
    __shared__ short Bs[128 * 32];
    int tid = threadIdx.x;
    int wave = tid >> 6, lane = tid & 63;
    int nbx = N >> 7;
    int bx = blockIdx.x % nbx, by = blockIdx.x / nbx;
    int row0 = by << 7, col0 = bx << 7;
    int wr = wave >> 1, wc = wave & 1;
    int fr = lane & 15, fq = lane >> 4;

    facc acc[4][4];
    facc zero = {0.f, 0.f, 0.f, 0.f};
    #pragma unroll
    for (int m = 0; m < 4; m++)
        #pragma unroll
        for (int n = 0; n < 4; n++) acc[m][n] = zero;

    MGEMM_CORE(A, Bt, K, row0, col0)

    #pragma unroll
    for (int m = 0; m < 4; m++) {
        #pragma unroll
        for (int n = 0; n < 4; n++) {
            #pragma unroll
            for (int r = 0; r < 4; r++) {
                int row = row0 + (wr << 6) + (m << 4) + (fq << 2) + r;
                int col = col0 + (wc << 6) + (n << 4) + fr;
                float v = acc[m][n][r];
                if (BIAS) v += bias[col];
                if (RELU) v = fmaxf(v, 0.f);
                if (RES == 1) v += res[(size_t)row * N + col];
                if (OUTMODE == 0) {
                    ((float*)out)[(size_t)row * N + col] = v;
                } else {
                    ((bf16*)out)[(size_t)row * N + col] = __float2bfloat16(v);
                }
            }
        }
    }
}

// ---------------------------------------------------------------------------
// Fused CA input projections: cq (act0bf@caWqt), ck/cv (encbf@caWkt dual).
// ---------------------------------------------------------------------------
__global__ __launch_bounds__(256) void mgemm3_k(
    const short* __restrict__ Aq, const short* __restrict__ Bq,
    const short* __restrict__ Akv, const short* __restrict__ Bkv,
    bf16* __restrict__ cq, bf16* __restrict__ ckv)
{
    __shared__ short As[128 * 32];
    __shared__ short Bs[128 * 32];
    int tid = threadIdx.x;
    int wave = tid >> 6, lane = tid & 63;
    int bx = blockIdx.x % 12, by = blockIdx.x / 12;
    int row0 = by << 7;
    bool isQ = (bx < 4);
    int col0 = (isQ ? bx : (bx - 4)) << 7;
    const short* A = isQ ? Aq : Akv;
    const short* Bt = isQ ? Bq : Bkv;
    int wr = wave >> 1, wc = wave & 1;
    int fr = lane & 15, fq = lane >> 4;

    facc acc[4][4];
    facc zero = {0.f, 0.f, 0.f, 0.f};
    #pragma unroll
    for (int m = 0; m < 4; m++)
        #pragma unroll
        for (int n = 0; n < 4; n++) acc[m][n] = zero;

    MGEMM_CORE(A, Bt, 512, row0, col0)

    #pragma unroll
    for (int m = 0; m < 4; m++) {
        #pragma unroll
        for (int n = 0; n < 4; n++) {
            #pragma unroll
            for (int r = 0; r < 4; r++) {
                int row = row0 + (wr << 6) + (m << 4) + (fq << 2) + r;
                int col = col0 + (wc << 6) + (n << 4) + fr;
                float v = acc[m][n][r];
                int b = row >> 12, s = row & (S_ - 1);
                if (isQ) {
                    int h = col >> 6, kk2 = col & 63;
                    cq[(((size_t)(b * H_ + h) * S_ + s) << 6) + kk2] = __float2bfloat16(v);
                } else {
                    int buf = col >> 9, cc = col & 511;
                    int h = cc >> 6, kk2 = cc & 63;
                    ckv[(size_t)buf * QKVSTRIDE +
                        (((size_t)(b * H_ + h) * S_ + s) << 6) + kk2] = __float2bfloat16(v);
                }
            }
        }
    }
}

// ---------------------------------------------------------------------------
// Batched weight prep: 6 transposed bf16 conversions in one dispatch.
// ---------------------------------------------------------------------------
__global__ __launch_bounds__(256) void prep_k(
    const float* __restrict__ ca_Wq, const float* __restrict__ ca_Wk,
    const float* __restrict__ ca_Wv, const float* __restrict__ ca_Wo,
    const float* __restrict__ ff_W1, const float* __restrict__ ff_W2,
    bf16* __restrict__ caWqt, bf16* __restrict__ caWkt,
    bf16* __restrict__ caWvt, bf16* __restrict__ caWot,
    bf16* __restrict__ ffW1t, bf16* __restrict__ ffW2t)
{
    int id = blockIdx.x;
    const float* W; bf16* Wt; int N, K; size_t i;
    if (id < 4096) {
        int w = id >> 10;
        W  = (w == 0) ? ca_Wq : (w == 1) ? ca_Wk : (w == 2) ? ca_Wv : ca_Wo;
        Wt = (w == 0) ? caWqt : (w == 1) ? caWkt : (w == 2) ? caWvt : caWot;
        N = 512; K = 512;
        i = (size_t)(id & 1023) * 256 + threadIdx.x;
    } else {
        int id2 = id - 4096;
        int w = id2 >> 12;
        W  = w ? ff_W2 : ff_W1;
        Wt = w ? ffW2t : ffW1t;
        N = w ? 512 : 2048; K = w ? 2048 : 512;
        i = (size_t)(id2 & 4095) * 256 + threadIdx.x;
    }
    int n = (int)(i / K), k = (int)(i % K);
    Wt[i] = __float2bfloat16(W[(size_t)k * N + n]);
}

// ---------------------------------------------------------------------------
// Batched wrot. Grid 1024.
// ---------------------------------------------------------------------------
__global__ __launch_bounds__(256) void wrot2_k(
    const float* __restrict__ Wq, const float* __restrict__ Wk,
    const float* __restrict__ rot,
    float* __restrict__ wq, float* __restrict__ wk)
{
    int z = blockIdx.x >> 9;
    int d = blockIdx.x & 511;
    const float* W = z ? Wk : Wq;
    float* wrot = z ? wk : wq;
    int t = threadIdx.x;
    int h = t >> 5, j = t & 31;
    float a = 0.f;
    #pragma unroll
    for (int k = 0; k < 64; k++)
        a += W[(size_t)(d * H_ + h) * 64 + k] * rot[(size_t)(h * 64 + k) * 32 + j];
    wrot[(size_t)d * 256 + t] = a;
}

__global__ __launch_bounds__(256) void cast_k(
    const float* __restrict__ x, bf16* __restrict__ y)
{
    size_t i = ((size_t)blockIdx.x * 256 + threadIdx.x) * 4;
    float4 v = *reinterpret_cast<const float4*>(x + i);
    y[i]     = __float2bfloat16(v.x);
    y[i + 1] = __float2bfloat16(v.y);
    y[i + 2] = __float2bfloat16(v.z);
    y[i + 3] = __float2bfloat16(v.w);
}

// ---------------------------------------------------------------------------
// SA hash, batched q+k.
// ---------------------------------------------------------------------------
__global__ __launch_bounds__(256) void hash2_k(
    const float* __restrict__ tq, const float* __restrict__ tk,
    const float* __restrict__ rot,
    int* __restrict__ bq, int* __restrict__ bk2)
{
    int z = blockIdx.x >> 9;
    int bid = blockIdx.x & 511;
    int bh = bid >> 4;
    int st = bid & 15;
    int h = bh % H_;
    const float* t = z ? tk : tq;
    int* bucket = z ? bk2 : bq;
    __shared__ float rs[64][32];
    int tid = threadIdx.x;
    for (int e = tid; e < 2048; e += 256)
        rs[e >> 5][e & 31] = rot[h * 2048 + e];
    __syncthreads();

    int s = st * 256 + tid;
    const float* qr = t + ((size_t)bh * S_ + s) * 64;
    float qv[64];
    #pragma unroll
    for (int i = 0; i < 64; i++) qv[i] = qr[i];
    float r[32];
    #pragma unroll
    for (int j = 0; j < 32; j++) {
        float a = 0.f;
        #pragma unroll
        for (int kk = 0; kk < 64; kk++) a += qv[kk] * rs[kk][j];
        r[j] = a;
    }
    float best = -INFINITY; int bi = 0;
    #pragma unroll
    for (int j = 0; j < 32; j++) { if (r[j] > best) { best = r[j]; bi = j; } }
    #pragma unroll
    for (int j = 0; j < 32; j++) { float v = -r[j]; if (v > best) { best = v; bi = 32 + j; } }
    bucket[(size_t)bh * S_ + s] = bi;
}

// ---------------------------------------------------------------------------
// Batched stable counting sort: 64 blocks.
// ---------------------------------------------------------------------------
__global__ __launch_bounds__(256) void sort2_k(
    const int* __restrict__ bq, int* __restrict__ pq,
    const int* __restrict__ bk2, int* __restrict__ pk)
{
    int z = blockIdx.x >> 5;
    int bh = blockIdx.x & 31;
    const int* bucket = z ? bk2 : bq;
    int* perm = z ? pk : pq;
    __shared__ int lb[S_];
    __shared__ int cnt[64 * 128];
    __shared__ int wtot[4];
    int tid = threadIdx.x;

    for (int i = tid; i < S_; i += 256) lb[i] = bucket[(size_t)bh * S_ + i];
    for (int i = tid; i < 8192; i += 256) cnt[i] = 0;
    __syncthreads();

    if (tid < 128) {
        int s0 = tid << 5;
        #pragma unroll
        for (int i = 0; i < 32; i++)
            cnt[(lb[s0 + i] << 7) + tid]++;
    }
    __syncthreads();

    int base = tid << 5;
    int tsum = 0;
    #pragma unroll
    for (int i = 0; i < 32; i++) tsum += cnt[base + i];
    int incl = tsum;
    #pragma unroll
    for (int off = 1; off < 64; off <<= 1) {
        int n = __shfl_up(incl, off, 64);
        if ((tid & 63) >= off) incl += n;
    }
    if ((tid & 63) == 63) wtot[tid >> 6] = incl;
    __syncthreads();
    int wbase = 0;
    for (int w = 0; w < (tid >> 6); w++) wbase += wtot[w];
    int run = wbase + incl - tsum;
    #pragma unroll
    for (int i = 0; i < 32; i++) {
        int c = cnt[base + i];
        cnt[base + i] = run;
        run += c;
    }
    __syncthreads();

    if (tid < 128) {
        int s0 = tid << 5;
        int* pr = perm + (size_t)bh * S_;
        #pragma unroll
        for (int i = 0; i < 32; i++) {
            int b = lb[s0 + i];
            int pos = cnt[(b << 7) + tid]++;
            pr[pos] = s0 + i;
        }
    }
}

// ---------------------------------------------------------------------------
// Chunked LSH attention: 4 waves/block, quad-per-query + async-V prefetch.
// ---------------------------------------------------------------------------
template<typename T, typename OT>
__global__ __launch_bounds__(256, 4) void attn_k(
    const T* __restrict__ q, const T* __restrict__ k,
    const T* __restrict__ v, const int* __restrict__ bq,
    const int* __restrict__ bk, const int* __restrict__ permq,
    const int* __restrict__ permk, OT* __restrict__ o)
{
    int c = blockIdx.x % NC_;
    int bh = blockIdx.x / NC_;
    int b = bh / H_, h = bh % H_;
    __shared__ float kv[128][64];
    __shared__ int skx[128];
    __shared__ int bkx[128];
    int tid = threadIdx.x;
    const int qq = tid >> 2, u = tid & 3;
    const size_t bhS = (size_t)bh * S_;

    if (tid < 128) {
        int sidx = (tid < 64) ? (((c + NC_ - 1) & (NC_ - 1)) * 64 + tid)
                              : (c * 64 + (tid - 64));
        int sk = permk[bhS + sidx];
        skx[tid] = sk;
        bkx[tid] = bk[bhS + sk];
    }
    __syncthreads();

    const int rr = tid >> 4, c4 = (tid & 15) << 2;
    #pragma unroll
    for (int pass = 0; pass < 8; pass++) {
        int row = pass * 16 + rr;
        *reinterpret_cast<float4*>(&kv[row][c4]) =
            ld4g(k + (bhS + skx[row]) * 64 + c4);
    }

    int sq = permq[bhS + c * 64 + qq];
    float4 qv[4];
    {
        const T* qr = q + (bhS + sq) * 64 + u * 16;
        #pragma unroll
        for (int i = 0; i < 4; i++) qv[i] = ld4g(qr + i * 4);
    }
    int bqi = bq[bhS + sq];
    __syncthreads();

    float4 vpre[8];
    #pragma unroll
    for (int pass = 0; pass < 8; pass++)
        vpre[pass] = ld4g(v + (bhS + skx[pass * 16 + rr]) * 64 + c4);

    float p[32];
    #pragma unroll
    for (int g = 0; g < 4; g++) {
        float part[32];
        #pragma unroll
        for (int t = 0; t < 32; t++) {
            const float4* kr = reinterpret_cast<const float4*>(&kv[g * 32 + t][u << 4]);
            float4 k0 = kr[0], k1 = kr[1], k2 = kr[2], k3 = kr[3];
            float s0 = qv[0].x * k0.x + qv[0].y * k0.y + qv[0].z * k0.z + qv[0].w * k0.w;
            float s1 = qv[1].x * k1.x + qv[1].y * k1.y + qv[1].z * k1.z + qv[1].w * k1.w;
            float s2 = qv[2].x * k2.x + qv[2].y * k2.y + qv[2].z * k2.z + qv[2].w * k2.w;
            float s3 = qv[3].x * k3.x + qv[3].y * k3.y + qv[3].z * k3.z + qv[3].w * k3.w;
            part[t] = (s0 + s1) + (s2 + s3);
        }
        float keep[16];
        #pragma unroll
        for (int t = 0; t < 16; t++) {
            float lo = __shfl_xor(part[t], 2, 64);
            float hi = __shfl_xor(part[16 + t], 2, 64);
            keep[t] = (u < 2) ? part[t] + lo : part[16 + t] + hi;
        }
        #pragma unroll
        for (int t = 0; t < 8; t++) {
            float lo = __shfl_xor(keep[t], 1, 64);
            float hi = __shfl_xor(keep[8 + t], 1, 64);
            float s = ((u & 1) == 0) ? keep[t] + lo : keep[8 + t] + hi;
            int j = g * 32 + (u >> 1) * 16 + (u & 1) * 8 + t;
            p[g * 8 + t] = (bqi == bkx[j]) ? s * 0.125f : -1e9f;
        }
    }

    float m = -INFINITY;
    #pragma unroll
    for (int i = 0; i < 32; i++) m = fmaxf(m, p[i]);
    m = fmaxf(m, __shfl_xor(m, 1, 64));
    m = fmaxf(m, __shfl_xor(m, 2, 64));
    float l = 0.f;
    #pragma unroll
    for (int i = 0; i < 32; i++) { p[i] = __expf(p[i] - m); l += p[i]; }
    l += __shfl_xor(l, 1, 64);
    l += __shfl_xor(l, 2, 64);

    __syncthreads();
    #pragma unroll
    for (int pass = 0; pass < 8; pass++)
        *reinterpret_cast<float4*>(&kv[pass * 16 + rr][c4]) = vpre[pass];
    __syncthreads();

    float4 acc0 = make_float4(0.f, 0.f, 0.f, 0.f);
    float4 acc1 = make_float4(0.f, 0.f, 0.f, 0.f);
    float4 acc2 = make_float4(0.f, 0.f, 0.f, 0.f);
    float4 acc3 = make_float4(0.f, 0.f, 0.f, 0.f);
    int base = tid & ~3;
    #pragma unroll
    for (int j = 0; j < 128; j++) {
        const int uo = ((j >> 3) & 1) | (((j >> 4) & 1) << 1);
        const int slot = ((j >> 5) << 3) | (j & 7);
        float pj = __shfl(p[slot], base + uo, 64);
        const float4* vr = reinterpret_cast<const float4*>(&kv[j][u << 4]);
        float4 v0 = vr[0], v1 = vr[1], v2 = vr[2], v3 = vr[3];
        acc0.x += pj * v0.x; acc0.y += pj * v0.y; acc0.z += pj * v0.z; acc0.w += pj * v0.w;
        acc1.x += pj * v1.x; acc1.y += pj * v1.y; acc1.z += pj * v1.z; acc1.w += pj * v1.w;
        acc2.x += pj * v2.x; acc2.y += pj * v2.y; acc2.z += pj * v2.z; acc2.w += pj * v2.w;
        acc3.x += pj * v3.x; acc3.y += pj * v3.y; acc3.z += pj * v3.z; acc3.w += pj * v3.w;
    }
    float inv = 1.0f / l;
    OT* orow = o + ((size_t)b * S_ + sq) * 512 + h * 64 + (u << 4);
    st4(orow + 0,  make_float4(acc0.x * inv, acc0.y * inv, acc0.z * inv, acc0.w * inv));
    st4(orow + 4,  make_float4(acc1.x * inv, acc1.y * inv, acc1.z * inv, acc1.w * inv));
    st4(orow + 8,  make_float4(acc2.x * inv, acc2.y * inv, acc2.z * inv, acc2.w * inv));
    st4(orow + 12, make_float4(acc3.x * inv, acc3.y * inv, acc3.z * inv, acc3.w * inv));
}

// ---------------------------------------------------------------------------
// LayerNorm per row of [M,512], f32 out (+ optional bf16 copy).
// ---------------------------------------------------------------------------
template<bool BFC>
__global__ __launch_bounds__(256) void ln_k(
    const float* __restrict__ x, const float* __restrict__ g,
    const float* __restrict__ bvec, float* __restrict__ out,
    bf16* __restrict__ bfout)
{
    int row = blockIdx.x;
    int tid = threadIdx.x;
    __shared__ float red[256];
    const float* xr = x + (size_t)row * D_;
    float v0 = xr[tid], v1 = xr[tid + 256];
    red[tid] = v0 + v1;
    __syncthreads();
    for (int off = 128; off > 0; off >>= 1) {
        if (tid < off) red[tid] += red[tid + off];
        __syncthreads();
    }
    float mean = red[0] / 512.f;
    __syncthreads();
    float d0 = v0 - mean, d1 = v1 - mean;
    red[tid] = d0 * d0 + d1 * d1;
    __syncthreads();
    for (int off = 128; off > 0; off >>= 1) {
        if (tid < off) red[tid] += red[tid + off];
        __syncthreads();
    }
    float var = red[0] / 512.f;
    float rs = 1.0f / sqrtf(var + 1e-5f);
    float y0 = d0 * rs * g[tid] + bvec[tid];
    float y1 = d1 * rs * g[tid + 256] + bvec[tid + 256];
    out[(size_t)row * D_ + tid] = y0;
    out[(size_t)row * D_ + tid + 256] = y1;
    if (BFC) {
        bfout[(size_t)row * D_ + tid] = __float2bfloat16(y0);
        bfout[(size_t)row * D_ + tid + 256] = __float2bfloat16(y1);
    }
}

// ---------------------------------------------------------------------------
extern "C" void kernel_launch(void* const* d_in, const int* in_sizes, int n_in,
                              void* d_out, int out_size, void* d_ws, size_t ws_size,
                              hipStream_t stream)
{
    (void)in_sizes; (void)n_in; (void)out_size; (void)ws_size;
    const float* dec   = (const float*)d_in[0];
    const float* enc   = (const float*)d_in[1];
    const float* sa_Wq = (const float*)d_in[2];
    const float* sa_Wk = (const float*)d_in[3];
    const float* sa_Wv = (const float*)d_in[4];
    const float* sa_Wo = (const float*)d_in[5];
    const float* sa_g  = (const float*)d_in[6];
    const float* sa_b  = (const float*)d_in[7];
    const float* sa_rot= (const float*)d_in[8];
    const float* ca_Wq = (const float*)d_in[9];
    const float* ca_Wk = (const float*)d_in[10];
    const float* ca_Wv = (const float*)d_in[11];
    const float* ca_Wo = (const float*)d_in[12];
    const float* ca_g  = (const float*)d_in[13];
    const float* ca_b  = (const float*)d_in[14];
    const float* ca_rot= (const float*)d_in[15];
    const float* ff_W1 = (const float*)d_in[16];
    const float* ff_b1 = (const float*)d_in[17];
    const float* ff_W2 = (const float*)d_in[18];
    const float* ff_b2 = (const float*)d_in[19];
    const float* ff_g  = (const float*)d_in[20];
    const float* ff_b  = (const float*)d_in[21];

    char* ws = (char*)d_ws;
    const size_t MB = 1ull << 20;
    float* qb     = (float*)(ws + 0);
    float* kb     = (float*)(ws + 32*MB);
    float* vb     = (float*)(ws + 64*MB);
    float* ob     = (float*)(ws + 96*MB);
    float* act0   = (float*)(ws + 128*MB);
    bf16*  act0bf = (bf16*)(ws + 160*MB);
    bf16*  cq     = (bf16*)(ws + 0);
    bf16*  ck     = (bf16*)(ws + 16*MB);
    bf16*  cv     = (bf16*)(ws + 32*MB);
    bf16*  caOut  = (bf16*)(ws + 48*MB);
    bf16*  encbf  = (bf16*)(ws + 64*MB);
    bf16*  act1bf = (bf16*)(ws + 80*MB);
    float* act1   = (float*)(ws + 96*MB);
    bf16*  hid    = (bf16*)(ws + 0);
    float* ffout  = (float*)(ws + 128*MB);
    bf16*  caWqt  = (bf16*)(ws + 176*MB);
    bf16*  caWkt  = (bf16*)(ws + 176*MB + 512*1024);
    bf16*  caWvt  = (bf16*)(ws + 177*MB);
    bf16*  caWot  = (bf16*)(ws + 177*MB + 512*1024);
    bf16*  ffW1t  = (bf16*)(ws + 178*MB);
    bf16*  ffW2t  = (bf16*)(ws + 180*MB);
    float* wrotq  = (float*)(ws + 182*MB);
    float* wrotk  = (float*)(ws + 182*MB + 512*1024);
    int*   bqb    = (int*)(ws + 183*MB);
    int*   bkb    = (int*)(ws + 183*MB + 512*1024);
    int*   pqb    = (int*)(ws + 184*MB);
    int*   pkb    = (int*)(ws + 184*MB + 512*1024);

    dim3 blk(256);
    const int g512  = (M_ / 128) * (512 / 128);
    const int g2048 = (M_ / 128) * (2048 / 128);

    // ---- batched converters ----
    wrot2_k<<<1024, blk, 0, stream>>>(ca_Wq, ca_Wk, ca_rot, wrotq, wrotk);
    prep_k<<<12288, blk, 0, stream>>>(ca_Wq, ca_Wk, ca_Wv, ca_Wo, ff_W1, ff_W2,
                                      caWqt, caWkt, caWvt, caWot, ffW1t, ffW2t);

    // ---------------- self-attention (all f32: hash-critical chain) ------
    gemmqkv_k<<<1536, blk, 0, stream>>>(dec, sa_Wq, sa_Wk, sa_Wv, qb);
    hash2_k<<<1024, blk, 0, stream>>>(qb, kb, sa_rot, bqb, bkb);
    sort2_k<<<64, blk, 0, stream>>>(bqb, pqb, bkb, pkb);
    attn_k<float,float><<<BH_ * NC_, blk, 0, stream>>>(qb, kb, vb, bqb, bkb, pqb, pkb, ob);
    gemm_k<<<g512, blk, 0, stream>>>(ob, sa_Wo, dec, act0, 512, 512);
    ln_k<true><<<M_, blk, 0, stream>>>(act0, sa_g, sa_b, act0, act0bf);

    // ---------------- cross-attention ----------------
    gemmproj_k<<<512, blk, 0, stream>>>(act0, wrotq, bqb, enc, wrotk, bkb);
    sort2_k<<<64, blk, 0, stream>>>(bqb, pqb, bkb, pkb);
    cast_k<<<M_ * 512 / 1024, blk, 0, stream>>>(enc, encbf);
    mgemm3_k<<<1536, blk, 0, stream>>>((const short*)act0bf, (const short*)caWqt,
                                       (const short*)encbf, (const short*)caWkt, cq, ck);
    attn_k<bf16,bf16><<<BH_ * NC_, blk, 0, stream>>>(cq, ck, cv, bqb, bkb, pqb, pkb, caOut);
    mgemm_k<0,1,false,false><<<g512, blk, 0, stream>>>((const short*)caOut, (const short*)caWot, nullptr, act0, act1, 512, 512);
    ln_k<true><<<M_, blk, 0, stream>>>(act1, ca_g, ca_b, act1, act1bf);

    // ---------------- feed-forward ----------------
    mgemm_k<1,0,true,true><<<g2048, blk, 0, stream>>>((const short*)act1bf, (const short*)ffW1t, ff_b1, nullptr, hid, 2048, 512);
    mgemm_k<0,1,true,false><<<g512, blk, 0, stream>>>((const short*)hid, (const short*)ffW2t, ff_b2, act1, ffout, 512, 2048);
    ln_k<false><<<M_, blk, 0, stream>>>(ffout, ff_g, ff_b, (float*)d_out, nullptr);
}

// Round 18
// 1030.218 us; speedup vs baseline: 1.0112x; 1.0112x over previous
//
#include <hip/hip_runtime.h>
#include <hip/hip_bf16.h>
#include <math.h>

typedef __hip_bfloat16 bf16;

#define B_ 4
#define S_ 4096
#define D_ 512
#define H_ 8
#define NC_ 64
#define M_ (B_*S_)     // 16384
#define BH_ (B_*H_)    // 32
#define QKVSTRIDE 8388608   // elems between qb/kb/vb (f32) and ck/cv (bf16)

typedef __attribute__((ext_vector_type(8))) short bfrag;
typedef __attribute__((ext_vector_type(4))) float facc;

static __device__ __forceinline__ float tof(float x){ return x; }
static __device__ __forceinline__ float tof(bf16 x){ return __bfloat162float(x); }

static __device__ __forceinline__ float4 ld4g(const float* p) {
    return *reinterpret_cast<const float4*>(p);
}
static __device__ __forceinline__ float4 ld4g(const bf16* p) {
    short4 s = *reinterpret_cast<const short4*>(p);
    float4 r;
    r.x = __bfloat162float(*reinterpret_cast<const bf16*>(&s.x));
    r.y = __bfloat162float(*reinterpret_cast<const bf16*>(&s.y));
    r.z = __bfloat162float(*reinterpret_cast<const bf16*>(&s.z));
    r.w = __bfloat162float(*reinterpret_cast<const bf16*>(&s.w));
    return r;
}
static __device__ __forceinline__ void st4(float* p, float4 v) {
    *reinterpret_cast<float4*>(p) = v;
}
static __device__ __forceinline__ void st4(bf16* p, float4 v) {
    bf16 b0 = __float2bfloat16(v.x), b1 = __float2bfloat16(v.y);
    bf16 b2 = __float2bfloat16(v.z), b3 = __float2bfloat16(v.w);
    short4 s;
    s.x = *reinterpret_cast<short*>(&b0);
    s.y = *reinterpret_cast<short*>(&b1);
    s.z = *reinterpret_cast<short*>(&b2);
    s.w = *reinterpret_cast<short*>(&b3);
    *reinterpret_cast<short4*>(p) = s;
}

#define GLL(gp, lp) __builtin_amdgcn_global_load_lds( \
    (const __attribute__((address_space(1))) void*)(gp), \
    (__attribute__((address_space(3))) void*)(lp), 16, 0, 0)

// ---------------------------------------------------------------------------
// Shared f32 GEMM block body (R8 config, best measured). Bit-identical
// accumulation order across all callers. PRECISION LEDGER: everything
// upstream of act0 (SA q/k/v, attn, Wo, proj) must be f32 — bf16-class
// noise anywhere in this chain flips CA hash buckets (R15/R16 failures).
// ---------------------------------------------------------------------------
#define F32_GEMM_BODY(A_, B_ptr, NB_, K_, row0_, col0_)                         \
    for (int k0 = 0; k0 < (K_); k0 += 32) {                                     \
        _Pragma("unroll")                                                       \
        for (int c = 0; c < 4; c++) {                                           \
            int e = c * 256 + tid;                                              \
            GLL((B_ptr) + (size_t)(k0 + (e >> 5)) * (NB_) + (col0_) + ((e & 31) << 2), \
                &Bs[c * 1024 + (wave << 8)]);                                   \
        }                                                                       \
        _Pragma("unroll")                                                       \
        for (int c = 0; c < 4; c++) {                                           \
            int e = c * 256 + tid;                                              \
            int r = e >> 3, k4 = (e & 7) << 2;                                  \
            float4 t4 = ld4g((A_) + (size_t)((row0_) + r) * (K_) + k0 + k4);    \
            At[k4 + 0][r] = t4.x;                                               \
            At[k4 + 1][r] = t4.y;                                               \
            At[k4 + 2][r] = t4.z;                                               \
            At[k4 + 3][r] = t4.w;                                               \
        }                                                                       \
        __syncthreads();                                                        \
        _Pragma("unroll")                                                       \
        for (int kk = 0; kk < 32; kk++) {                                       \
            float4 a0 = *reinterpret_cast<const float4*>(&At[kk][ty * 8]);      \
            float4 a1 = *reinterpret_cast<const float4*>(&At[kk][ty * 8 + 4]);  \
            float4 b0 = *reinterpret_cast<const float4*>(&Bs[kk * 128 + tx * 4]);\
            float4 b1 = *reinterpret_cast<const float4*>(&Bs[kk * 128 + 64 + tx * 4]);\
            float a[8] = {a0.x, a0.y, a0.z, a0.w, a1.x, a1.y, a1.z, a1.w};      \
            float bb[8] = {b0.x, b0.y, b0.z, b0.w, b1.x, b1.y, b1.z, b1.w};     \
            _Pragma("unroll")                                                   \
            for (int i = 0; i < 8; i++)                                         \
                _Pragma("unroll")                                               \
                for (int j = 0; j < 8; j++) acc[i][j] += a[i] * bb[j];          \
        }                                                                       \
        __syncthreads();                                                        \
    }

// ---------------------------------------------------------------------------
// f32 GEMM generic (sa_Wo path): C = A@B + res, f32 RM. N=512.
// ---------------------------------------------------------------------------
__global__ __launch_bounds__(256) void gemm_k(
    const float* __restrict__ A, const float* __restrict__ Bw,
    const float* __restrict__ res, float* __restrict__ out, int N, int K)
{
    __shared__ float At[32][132];
    __shared__ float Bs[32 * 128];
    int tid = threadIdx.x;
    int wave = tid >> 6;
    int nbx = N >> 7;
    int bx = blockIdx.x % nbx;
    int by = blockIdx.x / nbx;
    int row0 = by << 7, col0 = bx << 7;
    int ty = tid >> 4, tx = tid & 15;

    float acc[8][8];
    #pragma unroll
    for (int i = 0; i < 8; i++)
        #pragma unroll
        for (int j = 0; j < 8; j++) acc[i][j] = 0.f;

    F32_GEMM_BODY(A, Bw, N, K, row0, col0)

    #pragma unroll
    for (int i = 0; i < 8; i++) {
        int r = row0 + ty * 8 + i;
        #pragma unroll
        for (int j = 0; j < 8; j++) {
            int c = col0 + ((j >> 2) << 6) + tx * 4 + (j & 3);
            float v = acc[i][j];
            v += res[(size_t)r * N + c];
            out[(size_t)r * N + c] = v;
        }
    }
}

// ---------------------------------------------------------------------------
// Fused SA q/k/v GEMM (f32, hash-critical), XCD-chunked. 1536 blocks.
// ---------------------------------------------------------------------------
__global__ __launch_bounds__(256) void gemmqkv_k(
    const float* __restrict__ A, const float* __restrict__ W0,
    const float* __restrict__ W1, const float* __restrict__ W2,
    float* __restrict__ out)
{
    __shared__ float At[32][132];
    __shared__ float Bs[32 * 128];
    int tid = threadIdx.x;
    int wave = tid >> 6;
    int orig = blockIdx.x;
    int bid = (orig & 7) * 192 + (orig >> 3);   // bijective: 1536 = 8*192
    int bx = bid % 12;
    int by = bid / 12;
    int row0 = by << 7;
    int w = bx >> 2;
    int col0 = (bx & 3) << 7;
    const float* Bw = (w == 0) ? W0 : (w == 1) ? W1 : W2;
    float* outw = out + (size_t)w * QKVSTRIDE;
    int ty = tid >> 4, tx = tid & 15;

    float acc[8][8];
    #pragma unroll
    for (int i = 0; i < 8; i++)
        #pragma unroll
        for (int j = 0; j < 8; j++) acc[i][j] = 0.f;

    F32_GEMM_BODY(A, Bw, 512, 512, row0, col0)

    #pragma unroll
    for (int i = 0; i < 8; i++) {
        int r = row0 + ty * 8 + i;
        int b = r >> 12, s = r & (S_ - 1);
        #pragma unroll
        for (int j = 0; j < 8; j++) {
            int c = col0 + ((j >> 2) << 6) + tx * 4 + (j & 3);
            int h = c >> 6, kk2 = c & 63;
            outw[((size_t)(b * H_ + h) * S_ + s) * 64 + kk2] = acc[i][j];
        }
    }
}

// ---------------------------------------------------------------------------
// Batched hash projections WITH FUSED ARGMAX (R17, verified). z=0:
// act0@wrotq -> bq ; z=1: enc@wrotk -> bk. Bit-identical r values; argmax
// via lane-local scan + shfl_xor{1,2,4} with first-index tie-break.
// ---------------------------------------------------------------------------
__global__ __launch_bounds__(256) void gemmproj_k(
    const float* __restrict__ A0, const float* __restrict__ B0, int* __restrict__ bq,
    const float* __restrict__ A1, const float* __restrict__ B1, int* __restrict__ bk)
{
    __shared__ float At[32][132];
    __shared__ float Bs[32 * 128];
    int tid = threadIdx.x;
    int wave = tid >> 6;
    int z = blockIdx.x >> 8;
    int bid = blockIdx.x & 255;
    int bx = bid & 1;
    int by = bid >> 1;
    int row0 = by << 7, col0 = bx << 7;
    const float* A = z ? A1 : A0;
    const float* Bw = z ? B1 : B0;
    int* bucket = z ? bk : bq;
    int ty = tid >> 4, tx = tid & 15;

    float acc[8][8];
    #pragma unroll
    for (int i = 0; i < 8; i++)
        #pragma unroll
        for (int j = 0; j < 8; j++) acc[i][j] = 0.f;

    F32_GEMM_BODY(A, Bw, 256, 512, row0, col0)

    #pragma unroll
    for (int i = 0; i < 8; i++) {
        int r = row0 + ty * 8 + i;
        int b = r >> 12, s = r & (S_ - 1);
        #pragma unroll
        for (int half = 0; half < 2; half++) {
            float bv = -INFINITY; int bi = 0;
            #pragma unroll
            for (int jj4 = 0; jj4 < 4; jj4++) {
                float v = acc[i][half * 4 + jj4];
                int idx = (tx & 7) * 4 + jj4;
                if (v > bv) { bv = v; bi = idx; }
            }
            #pragma unroll
            for (int jj4 = 0; jj4 < 4; jj4++) {
                float v = -acc[i][half * 4 + jj4];
                int idx = 32 + (tx & 7) * 4 + jj4;
                if (v > bv) { bv = v; bi = idx; }
            }
            #pragma unroll
            for (int off = 1; off < 8; off <<= 1) {
                float ov = __shfl_xor(bv, off, 64);
                int oi = __shfl_xor(bi, off, 64);
                if (ov > bv || (ov == bv && oi < bi)) { bv = ov; bi = oi; }
            }
            if ((tx & 7) == 0) {
                int h = bx * 4 + half * 2 + (tx >> 3);
                bucket[((size_t)(b * H_ + h)) * S_ + s] = bi;
            }
        }
    }
}

// ---------------------------------------------------------------------------
// bf16 MFMA GEMM. OUTMODE: 0 f32 RM, 1 bf16 RM.
// ---------------------------------------------------------------------------
#define MGEMM_CORE(A_, Bt_, K_, row0_, col0_)                                   \
    const short* gA = (A_) + (size_t)((row0_) + (wave << 5) + (lane >> 2)) * (K_) + ((lane & 3) << 3); \
    const short* gB = (Bt_) + (size_t)((col0_) + (wave << 5) + (lane >> 2)) * (K_) + ((lane & 3) << 3); \
    for (int k0 = 0; k0 < (K_); k0 += 32) {                                     \
        GLL(gA + k0,                    &As[wave << 10]);                       \
        GLL(gA + k0 + (size_t)16 * (K_), &As[(wave << 10) + 512]);              \
        GLL(gB + k0,                    &Bs[wave << 10]);                       \
        GLL(gB + k0 + (size_t)16 * (K_), &Bs[(wave << 10) + 512]);              \
        __syncthreads();                                                        \
        bfrag av[4], bv[4];                                                     \
        _Pragma("unroll")                                                       \
        for (int m = 0; m < 4; m++)                                             \
            av[m] = *reinterpret_cast<const bfrag*>(&As[(((wr << 6) + (m << 4) + fr) << 5) + (fq << 3)]); \
        _Pragma("unroll")                                                       \
        for (int n = 0; n < 4; n++)                                             \
            bv[n] = *reinterpret_cast<const bfrag*>(&Bs[(((wc << 6) + (n << 4) + fr) << 5) + (fq << 3)]); \
        _Pragma("unroll")                                                       \
        for (int m = 0; m < 4; m++)                                             \
            _Pragma("unroll")                                                   \
            for (int n = 0; n < 4; n++)                                         \
                acc[m][n] = __builtin_amdgcn_mfma_f32_16x16x32_bf16(av[m], bv[n], acc[m][n], 0, 0, 0); \
        __syncthreads();                                                        \
    }

template<int OUTMODE, int RES, bool BIAS, bool RELU>
__global__ __launch_bounds__(256) void mgemm_k(
    const short* __restrict__ A, const short* __restrict__ Bt,
    const float* __restrict__ bias, const float* __restrict__ res,
    void* __restrict__ out, int N, int K)
{
    __shared__ short As[128 * 32];
    __shared__ short Bs[128 * 32];
    int tid = threadIdx.x;
    int wave = tid >> 6, lane = tid & 63;
    int nbx = N >> 7;
    int bx = blockIdx.x % nbx, by = blockIdx.x / nbx;
    int row0 = by << 7, col0 = bx << 7;
    int wr = wave >> 1, wc = wave & 1;
    int fr = lane & 15, fq = lane >> 4;

    facc acc[4][4];
    facc zero = {0.f, 0.f, 0.f, 0.f};
    #pragma unroll
    for (int m = 0; m < 4; m++)
        #pragma unroll
        for (int n = 0; n < 4; n++) acc[m][n] = zero;

    MGEMM_CORE(A, Bt, K, row0, col0)

    #pragma unroll
    for (int m = 0; m < 4; m++) {
        #pragma unroll
        for (int n = 0; n < 4; n++) {
            #pragma unroll
            for (int r = 0; r < 4; r++) {
                int row = row0 + (wr << 6) + (m << 4) + (fq << 2) + r;
                int col = col0 + (wc << 6) + (n << 4) + fr;
                float v = acc[m][n][r];
                if (BIAS) v += bias[col];
                if (RELU) v = fmaxf(v, 0.f);
                if (RES == 1) v += res[(size_t)row * N + col];
                if (OUTMODE == 0) {
                    ((float*)out)[(size_t)row * N + col] = v;
                } else {
                    ((bf16*)out)[(size_t)row * N + col] = __float2bfloat16(v);
                }
            }
        }
    }
}

// ---------------------------------------------------------------------------
// Fused CA input projections: cq (act0bf@caWqt), ck/cv (encbf@caWkt dual).
// ---------------------------------------------------------------------------
__global__ __launch_bounds__(256) void mgemm3_k(
    const short* __restrict__ Aq, const short* __restrict__ Bq,
    const short* __restrict__ Akv, const short* __restrict__ Bkv,
    bf16* __restrict__ cq, bf16* __restrict__ ckv)
{
    __shared__ short As[128 * 32];
    __shared__ short Bs[128 * 32];
    int tid = threadIdx.x;
    int wave = tid >> 6, lane = tid & 63;
    int bx = blockIdx.x % 12, by = blockIdx.x / 12;
    int row0 = by << 7;
    bool isQ = (bx < 4);
    int col0 = (isQ ? bx : (bx - 4)) << 7;
    const short* A = isQ ? Aq : Akv;
    const short* Bt = isQ ? Bq : Bkv;
    int wr = wave >> 1, wc = wave & 1;
    int fr = lane & 15, fq = lane >> 4;

    facc acc[4][4];
    facc zero = {0.f, 0.f, 0.f, 0.f};
    #pragma unroll
    for (int m = 0; m < 4; m++)
        #pragma unroll
        for (int n = 0; n < 4; n++) acc[m][n] = zero;

    MGEMM_CORE(A, Bt, 512, row0, col0)

    #pragma unroll
    for (int m = 0; m < 4; m++) {
        #pragma unroll
        for (int n = 0; n < 4; n++) {
            #pragma unroll
            for (int r = 0; r < 4; r++) {
                int row = row0 + (wr << 6) + (m << 4) + (fq << 2) + r;
                int col = col0 + (wc << 6) + (n << 4) + fr;
                float v = acc[m][n][r];
                int b = row >> 12, s = row & (S_ - 1);
                if (isQ) {
                    int h = col >> 6, kk2 = col & 63;
                    cq[(((size_t)(b * H_ + h) * S_ + s) << 6) + kk2] = __float2bfloat16(v);
                } else {
                    int buf = col >> 9, cc = col & 511;
                    int h = cc >> 6, kk2 = cc & 63;
                    ckv[(size_t)buf * QKVSTRIDE +
                        (((size_t)(b * H_ + h) * S_ + s) << 6) + kk2] = __float2bfloat16(v);
                }
            }
        }
    }
}

// ---------------------------------------------------------------------------
// Batched weight prep: 6 transposed bf16 conversions in one dispatch.
// ---------------------------------------------------------------------------
__global__ __launch_bounds__(256) void prep_k(
    const float* __restrict__ ca_Wq, const float* __restrict__ ca_Wk,
    const float* __restrict__ ca_Wv, const float* __restrict__ ca_Wo,
    const float* __restrict__ ff_W1, const float* __restrict__ ff_W2,
    bf16* __restrict__ caWqt, bf16* __restrict__ caWkt,
    bf16* __restrict__ caWvt, bf16* __restrict__ caWot,
    bf16* __restrict__ ffW1t, bf16* __restrict__ ffW2t)
{
    int id = blockIdx.x;
    const float* W; bf16* Wt; int N, K; size_t i;
    if (id < 4096) {
        int w = id >> 10;
        W  = (w == 0) ? ca_Wq : (w == 1) ? ca_Wk : (w == 2) ? ca_Wv : ca_Wo;
        Wt = (w == 0) ? caWqt : (w == 1) ? caWkt : (w == 2) ? caWvt : caWot;
        N = 512; K = 512;
        i = (size_t)(id & 1023) * 256 + threadIdx.x;
    } else {
        int id2 = id - 4096;
        int w = id2 >> 12;
        W  = w ? ff_W2 : ff_W1;
        Wt = w ? ffW2t : ffW1t;
        N = w ? 512 : 2048; K = w ? 2048 : 512;
        i = (size_t)(id2 & 4095) * 256 + threadIdx.x;
    }
    int n = (int)(i / K), k = (int)(i % K);
    Wt[i] = __float2bfloat16(W[(size_t)k * N + n]);
}

// ---------------------------------------------------------------------------
// Batched wrot. Grid 1024.
// ---------------------------------------------------------------------------
__global__ __launch_bounds__(256) void wrot2_k(
    const float* __restrict__ Wq, const float* __restrict__ Wk,
    const float* __restrict__ rot,
    float* __restrict__ wq, float* __restrict__ wk)
{
    int z = blockIdx.x >> 9;
    int d = blockIdx.x & 511;
    const float* W = z ? Wk : Wq;
    float* wrot = z ? wk : wq;
    int t = threadIdx.x;
    int h = t >> 5, j = t & 31;
    float a = 0.f;
    #pragma unroll
    for (int k = 0; k < 64; k++)
        a += W[(size_t)(d * H_ + h) * 64 + k] * rot[(size_t)(h * 64 + k) * 32 + j];
    wrot[(size_t)d * 256 + t] = a;
}

__global__ __launch_bounds__(256) void cast_k(
    const float* __restrict__ x, bf16* __restrict__ y)
{
    size_t i = ((size_t)blockIdx.x * 256 + threadIdx.x) * 4;
    float4 v = *reinterpret_cast<const float4*>(x + i);
    y[i]     = __float2bfloat16(v.x);
    y[i + 1] = __float2bfloat16(v.y);
    y[i + 2] = __float2bfloat16(v.z);
    y[i + 3] = __float2bfloat16(v.w);
}

// ---------------------------------------------------------------------------
// SA hash, batched q+k.
// ---------------------------------------------------------------------------
__global__ __launch_bounds__(256) void hash2_k(
    const float* __restrict__ tq, const float* __restrict__ tk,
    const float* __restrict__ rot,
    int* __restrict__ bq, int* __restrict__ bk2)
{
    int z = blockIdx.x >> 9;
    int bid = blockIdx.x & 511;
    int bh = bid >> 4;
    int st = bid & 15;
    int h = bh % H_;
    const float* t = z ? tk : tq;
    int* bucket = z ? bk2 : bq;
    __shared__ float rs[64][32];
    int tid = threadIdx.x;
    for (int e = tid; e < 2048; e += 256)
        rs[e >> 5][e & 31] = rot[h * 2048 + e];
    __syncthreads();

    int s = st * 256 + tid;
    const float* qr = t + ((size_t)bh * S_ + s) * 64;
    float qv[64];
    #pragma unroll
    for (int i = 0; i < 64; i++) qv[i] = qr[i];
    float r[32];
    #pragma unroll
    for (int j = 0; j < 32; j++) {
        float a = 0.f;
        #pragma unroll
        for (int kk = 0; kk < 64; kk++) a += qv[kk] * rs[kk][j];
        r[j] = a;
    }
    float best = -INFINITY; int bi = 0;
    #pragma unroll
    for (int j = 0; j < 32; j++) { if (r[j] > best) { best = r[j]; bi = j; } }
    #pragma unroll
    for (int j = 0; j < 32; j++) { float v = -r[j]; if (v > best) { best = v; bi = 32 + j; } }
    bucket[(size_t)bh * S_ + s] = bi;
}

// ---------------------------------------------------------------------------
// Batched stable counting sort: 64 blocks.
// ---------------------------------------------------------------------------
__global__ __launch_bounds__(256) void sort2_k(
    const int* __restrict__ bq, int* __restrict__ pq,
    const int* __restrict__ bk2, int* __restrict__ pk)
{
    int z = blockIdx.x >> 5;
    int bh = blockIdx.x & 31;
    const int* bucket = z ? bk2 : bq;
    int* perm = z ? pk : pq;
    __shared__ int lb[S_];
    __shared__ int cnt[64 * 128];
    __shared__ int wtot[4];
    int tid = threadIdx.x;

    for (int i = tid; i < S_; i += 256) lb[i] = bucket[(size_t)bh * S_ + i];
    for (int i = tid; i < 8192; i += 256) cnt[i] = 0;
    __syncthreads();

    if (tid < 128) {
        int s0 = tid << 5;
        #pragma unroll
        for (int i = 0; i < 32; i++)
            cnt[(lb[s0 + i] << 7) + tid]++;
    }
    __syncthreads();

    int base = tid << 5;
    int tsum = 0;
    #pragma unroll
    for (int i = 0; i < 32; i++) tsum += cnt[base + i];
    int incl = tsum;
    #pragma unroll
    for (int off = 1; off < 64; off <<= 1) {
        int n = __shfl_up(incl, off, 64);
        if ((tid & 63) >= off) incl += n;
    }
    if ((tid & 63) == 63) wtot[tid >> 6] = incl;
    __syncthreads();
    int wbase = 0;
    for (int w = 0; w < (tid >> 6); w++) wbase += wtot[w];
    int run = wbase + incl - tsum;
    #pragma unroll
    for (int i = 0; i < 32; i++) {
        int c = cnt[base + i];
        cnt[base + i] = run;
        run += c;
    }
    __syncthreads();

    if (tid < 128) {
        int s0 = tid << 5;
        int* pr = perm + (size_t)bh * S_;
        #pragma unroll
        for (int i = 0; i < 32; i++) {
            int b = lb[s0 + i];
            int pos = cnt[(b << 7) + tid]++;
            pr[pos] = s0 + i;
        }
    }
}

// ---------------------------------------------------------------------------
// Chunked LSH attention: 4 waves/block, quad-per-query + async-V prefetch.
// Round 18: XCD-chunked blockIdx swizzle (bijective, 2048 = 8*256) so all
// 64 chunks of each (b,h) panel land on ONE XCD: the 2x K/V row reuse
// between adjacent chunks becomes a per-XCD L2 hit instead of an HBM
// re-gather. Pure remap — numerics bit-identical.
// ---------------------------------------------------------------------------
template<typename T, typename OT>
__global__ __launch_bounds__(256, 4) void attn_k(
    const T* __restrict__ q, const T* __restrict__ k,
    const T* __restrict__ v, const int* __restrict__ bq,
    const int* __restrict__ bk, const int* __restrict__ permq,
    const int* __restrict__ permk, OT* __restrict__ o)
{
    int orig = blockIdx.x;
    int swz = (orig & 7) * 256 + (orig >> 3);   // bijective XCD-chunk map
    int c = swz % NC_;
    int bh = swz / NC_;
    int b = bh / H_, h = bh % H_;
    __shared__ float kv[128][64];
    __shared__ int skx[128];
    __shared__ int bkx[128];
    int tid = threadIdx.x;
    const int qq = tid >> 2, u = tid & 3;
    const size_t bhS = (size_t)bh * S_;

    if (tid < 128) {
        int sidx = (tid < 64) ? (((c + NC_ - 1) & (NC_ - 1)) * 64 + tid)
                              : (c * 64 + (tid - 64));
        int sk = permk[bhS + sidx];
        skx[tid] = sk;
        bkx[tid] = bk[bhS + sk];
    }
    __syncthreads();

    const int rr = tid >> 4, c4 = (tid & 15) << 2;
    #pragma unroll
    for (int pass = 0; pass < 8; pass++) {
        int row = pass * 16 + rr;
        *reinterpret_cast<float4*>(&kv[row][c4]) =
            ld4g(k + (bhS + skx[row]) * 64 + c4);
    }

    int sq = permq[bhS + c * 64 + qq];
    float4 qv[4];
    {
        const T* qr = q + (bhS + sq) * 64 + u * 16;
        #pragma unroll
        for (int i = 0; i < 4; i++) qv[i] = ld4g(qr + i * 4);
    }
    int bqi = bq[bhS + sq];
    __syncthreads();

    float4 vpre[8];
    #pragma unroll
    for (int pass = 0; pass < 8; pass++)
        vpre[pass] = ld4g(v + (bhS + skx[pass * 16 + rr]) * 64 + c4);

    float p[32];
    #pragma unroll
    for (int g = 0; g < 4; g++) {
        float part[32];
        #pragma unroll
        for (int t = 0; t < 32; t++) {
            const float4* kr = reinterpret_cast<const float4*>(&kv[g * 32 + t][u << 4]);
            float4 k0 = kr[0], k1 = kr[1], k2 = kr[2], k3 = kr[3];
            float s0 = qv[0].x * k0.x + qv[0].y * k0.y + qv[0].z * k0.z + qv[0].w * k0.w;
            float s1 = qv[1].x * k1.x + qv[1].y * k1.y + qv[1].z * k1.z + qv[1].w * k1.w;
            float s2 = qv[2].x * k2.x + qv[2].y * k2.y + qv[2].z * k2.z + qv[2].w * k2.w;
            float s3 = qv[3].x * k3.x + qv[3].y * k3.y + qv[3].z * k3.z + qv[3].w * k3.w;
            part[t] = (s0 + s1) + (s2 + s3);
        }
        float keep[16];
        #pragma unroll
        for (int t = 0; t < 16; t++) {
            float lo = __shfl_xor(part[t], 2, 64);
            float hi = __shfl_xor(part[16 + t], 2, 64);
            keep[t] = (u < 2) ? part[t] + lo : part[16 + t] + hi;
        }
        #pragma unroll
        for (int t = 0; t < 8; t++) {
            float lo = __shfl_xor(keep[t], 1, 64);
            float hi = __shfl_xor(keep[8 + t], 1, 64);
            float s = ((u & 1) == 0) ? keep[t] + lo : keep[8 + t] + hi;
            int j = g * 32 + (u >> 1) * 16 + (u & 1) * 8 + t;
            p[g * 8 + t] = (bqi == bkx[j]) ? s * 0.125f : -1e9f;
        }
    }

    float m = -INFINITY;
    #pragma unroll
    for (int i = 0; i < 32; i++) m = fmaxf(m, p[i]);
    m = fmaxf(m, __shfl_xor(m, 1, 64));
    m = fmaxf(m, __shfl_xor(m, 2, 64));
    float l = 0.f;
    #pragma unroll
    for (int i = 0; i < 32; i++) { p[i] = __expf(p[i] - m); l += p[i]; }
    l += __shfl_xor(l, 1, 64);
    l += __shfl_xor(l, 2, 64);

    __syncthreads();
    #pragma unroll
    for (int pass = 0; pass < 8; pass++)
        *reinterpret_cast<float4*>(&kv[pass * 16 + rr][c4]) = vpre[pass];
    __syncthreads();

    float4 acc0 = make_float4(0.f, 0.f, 0.f, 0.f);
    float4 acc1 = make_float4(0.f, 0.f, 0.f, 0.f);
    float4 acc2 = make_float4(0.f, 0.f, 0.f, 0.f);
    float4 acc3 = make_float4(0.f, 0.f, 0.f, 0.f);
    int base = tid & ~3;
    #pragma unroll
    for (int j = 0; j < 128; j++) {
        const int uo = ((j >> 3) & 1) | (((j >> 4) & 1) << 1);
        const int slot = ((j >> 5) << 3) | (j & 7);
        float pj = __shfl(p[slot], base + uo, 64);
        const float4* vr = reinterpret_cast<const float4*>(&kv[j][u << 4]);
        float4 v0 = vr[0], v1 = vr[1], v2 = vr[2], v3 = vr[3];
        acc0.x += pj * v0.x; acc0.y += pj * v0.y; acc0.z += pj * v0.z; acc0.w += pj * v0.w;
        acc1.x += pj * v1.x; acc1.y += pj * v1.y; acc1.z += pj * v1.z; acc1.w += pj * v1.w;
        acc2.x += pj * v2.x; acc2.y += pj * v2.y; acc2.z += pj * v2.z; acc2.w += pj * v2.w;
        acc3.x += pj * v3.x; acc3.y += pj * v3.y; acc3.z += pj * v3.z; acc3.w += pj * v3.w;
    }
    float inv = 1.0f / l;
    OT* orow = o + ((size_t)b * S_ + sq) * 512 + h * 64 + (u << 4);
    st4(orow + 0,  make_float4(acc0.x * inv, acc0.y * inv, acc0.z * inv, acc0.w * inv));
    st4(orow + 4,  make_float4(acc1.x * inv, acc1.y * inv, acc1.z * inv, acc1.w * inv));
    st4(orow + 8,  make_float4(acc2.x * inv, acc2.y * inv, acc2.z * inv, acc2.w * inv));
    st4(orow + 12, make_float4(acc3.x * inv, acc3.y * inv, acc3.z * inv, acc3.w * inv));
}

// ---------------------------------------------------------------------------
// LayerNorm per row of [M,512], f32 out (+ optional bf16 copy).
// ---------------------------------------------------------------------------
template<bool BFC>
__global__ __launch_bounds__(256) void ln_k(
    const float* __restrict__ x, const float* __restrict__ g,
    const float* __restrict__ bvec, float* __restrict__ out,
    bf16* __restrict__ bfout)
{
    int row = blockIdx.x;
    int tid = threadIdx.x;
    __shared__ float red[256];
    const float* xr = x + (size_t)row * D_;
    float v0 = xr[tid], v1 = xr[tid + 256];
    red[tid] = v0 + v1;
    __syncthreads();
    for (int off = 128; off > 0; off >>= 1) {
        if (tid < off) red[tid] += red[tid + off];
        __syncthreads();
    }
    float mean = red[0] / 512.f;
    __syncthreads();
    float d0 = v0 - mean, d1 = v1 - mean;
    red[tid] = d0 * d0 + d1 * d1;
    __syncthreads();
    for (int off = 128; off > 0; off >>= 1) {
        if (tid < off) red[tid] += red[tid + off];
        __syncthreads();
    }
    float var = red[0] / 512.f;
    float rs = 1.0f / sqrtf(var + 1e-5f);
    float y0 = d0 * rs * g[tid] + bvec[tid];
    float y1 = d1 * rs * g[tid + 256] + bvec[tid + 256];
    out[(size_t)row * D_ + tid] = y0;
    out[(size_t)row * D_ + tid + 256] = y1;
    if (BFC) {
        bfout[(size_t)row * D_ + tid] = __float2bfloat16(y0);
        bfout[(size_t)row * D_ + tid + 256] = __float2bfloat16(y1);
    }
}

// ---------------------------------------------------------------------------
extern "C" void kernel_launch(void* const* d_in, const int* in_sizes, int n_in,
                              void* d_out, int out_size, void* d_ws, size_t ws_size,
                              hipStream_t stream)
{
    (void)in_sizes; (void)n_in; (void)out_size; (void)ws_size;
    const float* dec   = (const float*)d_in[0];
    const float* enc   = (const float*)d_in[1];
    const float* sa_Wq = (const float*)d_in[2];
    const float* sa_Wk = (const float*)d_in[3];
    const float* sa_Wv = (const float*)d_in[4];
    const float* sa_Wo = (const float*)d_in[5];
    const float* sa_g  = (const float*)d_in[6];
    const float* sa_b  = (const float*)d_in[7];
    const float* sa_rot= (const float*)d_in[8];
    const float* ca_Wq = (const float*)d_in[9];
    const float* ca_Wk = (const float*)d_in[10];
    const float* ca_Wv = (const float*)d_in[11];
    const float* ca_Wo = (const float*)d_in[12];
    const float* ca_g  = (const float*)d_in[13];
    const float* ca_b  = (const float*)d_in[14];
    const float* ca_rot= (const float*)d_in[15];
    const float* ff_W1 = (const float*)d_in[16];
    const float* ff_b1 = (const float*)d_in[17];
    const float* ff_W2 = (const float*)d_in[18];
    const float* ff_b2 = (const float*)d_in[19];
    const float* ff_g  = (const float*)d_in[20];
    const float* ff_b  = (const float*)d_in[21];

    char* ws = (char*)d_ws;
    const size_t MB = 1ull << 20;
    float* qb     = (float*)(ws + 0);
    float* kb     = (float*)(ws + 32*MB);
    float* vb     = (float*)(ws + 64*MB);
    float* ob     = (float*)(ws + 96*MB);
    float* act0   = (float*)(ws + 128*MB);
    bf16*  act0bf = (bf16*)(ws + 160*MB);
    bf16*  cq     = (bf16*)(ws + 0);
    bf16*  ck     = (bf16*)(ws + 16*MB);
    bf16*  cv     = (bf16*)(ws + 32*MB);
    bf16*  caOut  = (bf16*)(ws + 48*MB);
    bf16*  encbf  = (bf16*)(ws + 64*MB);
    bf16*  act1bf = (bf16*)(ws + 80*MB);
    float* act1   = (float*)(ws + 96*MB);
    bf16*  hid    = (bf16*)(ws + 0);
    float* ffout  = (float*)(ws + 128*MB);
    bf16*  caWqt  = (bf16*)(ws + 176*MB);
    bf16*  caWkt  = (bf16*)(ws + 176*MB + 512*1024);
    bf16*  caWvt  = (bf16*)(ws + 177*MB);
    bf16*  caWot  = (bf16*)(ws + 177*MB + 512*1024);
    bf16*  ffW1t  = (bf16*)(ws + 178*MB);
    bf16*  ffW2t  = (bf16*)(ws + 180*MB);
    float* wrotq  = (float*)(ws + 182*MB);
    float* wrotk  = (float*)(ws + 182*MB + 512*1024);
    int*   bqb    = (int*)(ws + 183*MB);
    int*   bkb    = (int*)(ws + 183*MB + 512*1024);
    int*   pqb    = (int*)(ws + 184*MB);
    int*   pkb    = (int*)(ws + 184*MB + 512*1024);

    dim3 blk(256);
    const int g512  = (M_ / 128) * (512 / 128);
    const int g2048 = (M_ / 128) * (2048 / 128);

    // ---- batched converters ----
    wrot2_k<<<1024, blk, 0, stream>>>(ca_Wq, ca_Wk, ca_rot, wrotq, wrotk);
    prep_k<<<12288, blk, 0, stream>>>(ca_Wq, ca_Wk, ca_Wv, ca_Wo, ff_W1, ff_W2,
                                      caWqt, caWkt, caWvt, caWot, ffW1t, ffW2t);

    // ---------------- self-attention (all f32: hash-critical chain) ------
    gemmqkv_k<<<1536, blk, 0, stream>>>(dec, sa_Wq, sa_Wk, sa_Wv, qb);
    hash2_k<<<1024, blk, 0, stream>>>(qb, kb, sa_rot, bqb, bkb);
    sort2_k<<<64, blk, 0, stream>>>(bqb, pqb, bkb, pkb);
    attn_k<float,float><<<BH_ * NC_, blk, 0, stream>>>(qb, kb, vb, bqb, bkb, pqb, pkb, ob);
    gemm_k<<<g512, blk, 0, stream>>>(ob, sa_Wo, dec, act0, 512, 512);
    ln_k<true><<<M_, blk, 0, stream>>>(act0, sa_g, sa_b, act0, act0bf);

    // ---------------- cross-attention ----------------
    gemmproj_k<<<512, blk, 0, stream>>>(act0, wrotq, bqb, enc, wrotk, bkb);
    sort2_k<<<64, blk, 0, stream>>>(bqb, pqb, bkb, pkb);
    cast_k<<<M_ * 512 / 1024, blk, 0, stream>>>(enc, encbf);
    mgemm3_k<<<1536, blk, 0, stream>>>((const short*)act0bf, (const short*)caWqt,
                                       (const short*)encbf, (const short*)caWkt, cq, ck);
    attn_k<bf16,bf16><<<BH_ * NC_, blk, 0, stream>>>(cq, ck, cv, bqb, bkb, pqb, pkb, caOut);
    mgemm_k<0,1,false,false><<<g512, blk, 0, stream>>>((const short*)caOut, (const short*)caWot, nullptr, act0, act1, 512, 512);
    ln_k<true><<<M_, blk, 0, stream>>>(act1, ca_g, ca_b, act1, act1bf);

    // ---------------- feed-forward ----------------
    mgemm_k<1,0,true,true><<<g2048, blk, 0, stream>>>((const short*)act1bf, (const short*)ffW1t, ff_b1, nullptr, hid, 2048, 512);
    mgemm_k<0,1,true,false><<<g512, blk, 0, stream>>>((const short*)hid, (const short*)ffW2t, ff_b2, act1, ffout, 512, 2048);
    ln_k<false><<<M_, blk, 0, stream>>>(ffout, ff_g, ff_b, (float*)d_out, nullptr);
}